// Round 1
// baseline (276.055 us; speedup 1.0000x reference)
//
#include <hip/hip_runtime.h>
#include <math.h>

#define KK 16
#define DD 16
#define NCAT 136
#define NROWS 20480
#define EPSF 1e-6f
#define LOG2PI_F 1.8378770664093453f
#define INV_SQRT2 0.70710678118654752f

// ---------------------------------------------------------------------------
// Main kernel: one thread per row (block = 1 wave of 64, grid = 320 blocks).
// Per-block setup: load mu into LDS, compute log-softmax(pi) and per-category
// constants. Per-row: g[k] = z . mu[:,k], zz = |z|^2, then a fully-unrolled
// 136-category scalar loop with online logsumexp (4 interleaved accumulators).
// ---------------------------------------------------------------------------
__global__ __launch_bounds__(64) void latent_main(
    const float* __restrict__ z,
    const float* __restrict__ pi,
    const float* __restrict__ mu,
    float* __restrict__ partials)
{
    __shared__ float mu_s[DD * KK];
    __shared__ float sRecip[NCAT];  // 1/inv_sig (0 on diagonal)
    __shared__ float sInv[NCAT];    // inv_sig
    __shared__ float sSq[NCAT];     // sqrt(clip(inv_sig,1e-12,1e30))
    __shared__ float sC[NCAT];      // dot(alpha, mu_B)
    __shared__ float sMB2[NCAT];    // sum(mu_B^2)
    __shared__ float sK0[NCAT];     // folded constant term per category

    const int tid = threadIdx.x;

    // --- load mu into LDS ---
    #pragma unroll
    for (int i = 0; i < 4; ++i) mu_s[tid + 64 * i] = mu[tid + 64 * i];

    // --- log-softmax(pi) via single-wave shuffle reductions ---
    float pv[3];
    float lmax = -1e30f;
    #pragma unroll
    for (int j = 0; j < 3; ++j) {
        int c = tid + j * 64;
        pv[j] = (c < NCAT) ? pi[c] : -1e30f;
        lmax = fmaxf(lmax, pv[j]);
    }
    #pragma unroll
    for (int off = 32; off > 0; off >>= 1)
        lmax = fmaxf(lmax, __shfl_xor(lmax, off, 64));
    float lsum = 0.f;
    #pragma unroll
    for (int j = 0; j < 3; ++j) {
        int c = tid + j * 64;
        if (c < NCAT) lsum += __expf(pv[j] - lmax);
    }
    #pragma unroll
    for (int off = 32; off > 0; off >>= 1)
        lsum += __shfl_xor(lsum, off, 64);

    __syncthreads();  // mu_s visible

    // --- per-category constants ---
    #pragma unroll
    for (int j = 0; j < 3; ++j) {
        int c = tid + j * 64;
        if (c < NCAT) {
            // invert triu row-major index c -> (a, b), a <= b
            int a = 0, rem = c;
            while (rem >= KK - a) { rem -= KK - a; ++a; }
            int b = a + rem;

            float inv = 0.f, Cc = 0.f, mb2 = 0.f;
            for (int d = 0; d < DD; ++d) {
                float mb = mu_s[d * KK + b];
                float ma = mu_s[d * KK + a];
                float al = mb - ma;
                inv += al * al;
                Cc  += al * mb;
                mb2 += mb * mb;
            }
            float recip  = (inv == 0.f) ? 0.f : 1.f / inv;
            float clipped = fminf(fmaxf(inv, 1e-12f), 1e30f);

            // log(clip(softmax(pi), EPS, 1))
            float p = __expf(pv[j] - lmax) / lsum;
            p = fminf(fmaxf(p, EPSF), 1.0f);
            float logpi = __logf(p);

            float k0;
            if (inv == 0.f)
                k0 = logpi - 8.f * LOG2PI_F;                                   // diagonal branch
            else
                k0 = logpi - 8.f * LOG2PI_F + 0.5f * (LOG2PI_F - __logf(clipped));

            sRecip[c] = recip;
            sInv[c]   = inv;
            sSq[c]    = sqrtf(clipped);
            sC[c]     = Cc;
            sMB2[c]   = mb2;
            sK0[c]    = k0;
        }
    }
    __syncthreads();

    // --- per-row computation ---
    const int row = blockIdx.x * 64 + tid;
    float lp = 0.f;
    if (row < NROWS) {
        const float* zr = z + row * DD;
        float zv[DD];
        #pragma unroll
        for (int i = 0; i < 4; ++i) {
            float4 v = reinterpret_cast<const float4*>(zr)[i];
            zv[4 * i + 0] = v.x; zv[4 * i + 1] = v.y;
            zv[4 * i + 2] = v.z; zv[4 * i + 3] = v.w;
        }
        float zz = 0.f;
        #pragma unroll
        for (int d = 0; d < DD; ++d) zz += zv[d] * zv[d];

        float g[KK];
        #pragma unroll
        for (int k = 0; k < KK; ++k) g[k] = 0.f;
        #pragma unroll
        for (int d = 0; d < DD; ++d) {
            #pragma unroll
            for (int k4 = 0; k4 < 4; ++k4) {
                float4 mrow = *reinterpret_cast<const float4*>(&mu_s[d * KK + 4 * k4]);
                g[4 * k4 + 0] += mrow.x * zv[d];
                g[4 * k4 + 1] += mrow.y * zv[d];
                g[4 * k4 + 2] += mrow.z * zv[d];
                g[4 * k4 + 3] += mrow.w * zv[d];
            }
        }

        // online logsumexp over 136 categories, 4 interleaved accumulators
        float m[4] = { -1e30f, -1e30f, -1e30f, -1e30f };
        float s[4] = { 0.f, 0.f, 0.f, 0.f };
        int c = 0;
        #pragma unroll
        for (int a = 0; a < KK; ++a) {
            #pragma unroll
            for (int b = a; b < KK; ++b) {
                float gb  = g[b];                      // static indices (full unroll)
                float sab = gb - g[a] - sC[c];
                float nu  = -sab * sRecip[c];
                float bsq = zz - 2.f * gb + sMB2[c];
                float val;
                if (a == b) {                          // compile-time branch: inv_sig == 0
                    val = sK0[c] - 0.5f * bsq;
                } else {
                    float t  = nu * nu * sInv[c] - bsq;
                    float sq = sSq[c];
                    float e1 = (1.f - nu) * sq * INV_SQRT2;
                    float e2 = (-nu) * sq * INV_SQRT2;
                    float cd = 0.5f * (erff(e1) - erff(e2));
                    cd = fminf(fmaxf(cd, EPSF), 1e30f);
                    val = sK0[c] + 0.5f * t + __logf(cd);
                }
                const int q = c & 3;                   // compile-time under unroll
                float nm = fmaxf(m[q], val);
                s[q] = s[q] * __expf(m[q] - nm) + __expf(val - nm);
                m[q] = nm;
                ++c;
            }
        }
        float M = fmaxf(fmaxf(m[0], m[1]), fmaxf(m[2], m[3]));
        float S = s[0] * __expf(m[0] - M) + s[1] * __expf(m[1] - M)
                + s[2] * __expf(m[2] - M) + s[3] * __expf(m[3] - M);
        lp = M + __logf(S);
    }

    // --- single-wave block reduction ---
    #pragma unroll
    for (int off = 32; off > 0; off >>= 1)
        lp += __shfl_xor(lp, off, 64);
    if (tid == 0) partials[blockIdx.x] = lp;
}

// ---------------------------------------------------------------------------
// Final reduction: sum 320 block partials, divide by NROWS.
// ---------------------------------------------------------------------------
__global__ __launch_bounds__(64) void latent_reduce(
    const float* __restrict__ partials, float* __restrict__ out, int n)
{
    const int tid = threadIdx.x;
    float s = 0.f;
    for (int i = tid; i < n; i += 64) s += partials[i];
    #pragma unroll
    for (int off = 32; off > 0; off >>= 1)
        s += __shfl_xor(s, off, 64);
    if (tid == 0) out[0] = s * (1.0f / (float)NROWS);
}

extern "C" void kernel_launch(void* const* d_in, const int* in_sizes, int n_in,
                              void* d_out, int out_size, void* d_ws, size_t ws_size,
                              hipStream_t stream) {
    const float* z  = (const float*)d_in[0];   // (2048,10,16) f32
    const float* pi = (const float*)d_in[1];   // (1,136) f32
    const float* mu = (const float*)d_in[2];   // (16,16) f32
    float* out      = (float*)d_out;           // scalar f32
    float* partials = (float*)d_ws;

    const int nblocks = NROWS / 64;            // 320
    latent_main<<<nblocks, 64, 0, stream>>>(z, pi, mu, partials);
    latent_reduce<<<1, 64, 0, stream>>>(partials, out, nblocks);
}

// Round 2
// 23.994 us; speedup vs baseline: 11.5053x; 11.5053x over previous
//
#include <hip/hip_runtime.h>
#include <math.h>

#define KK 16
#define DD 16
#define NCAT 136
#define NROWS 20480
#define NW 8            // waves per block
#define CPW 17          // categories per wave (8*17 = 136)
#define GS 17           // padded LDS stride for g (odd -> conflict-free)
#define EPSF 1e-6f
#define LOG2PI_F 1.8378770664093453f
#define INV_SQRT2 0.70710678118654752f

// ---------------------------------------------------------------------------
// Block = 512 threads = 8 waves, owns 64 rows. Wave w handles categories
// [17w, 17w+17) for row = lane. g[row][k] = z_row . mu[:,k] lives in LDS
// (computed cooperatively: wave w computes columns 2w, 2w+1). Per-category
// constants from mu/pi computed once per block by threads 0..135.
// Per-wave online-logsumexp partials merged via LDS by wave 0.
// ---------------------------------------------------------------------------
__global__ __launch_bounds__(512) void latent_main(
    const float* __restrict__ z,
    const float* __restrict__ pi,
    const float* __restrict__ mu,
    float* __restrict__ partials)
{
    __shared__ float g_s[64 * GS];
    __shared__ float zz_s[64];
    __shared__ float sRecip[NCAT];  // 1/inv_sig (0 on diagonal)
    __shared__ float sInv[NCAT];    // inv_sig
    __shared__ float sSq[NCAT];     // sqrt(clip(inv_sig))
    __shared__ float sC[NCAT];      // dot(alpha, mu_B)
    __shared__ float sMB2[NCAT];    // sum(mu_B^2)
    __shared__ float sK0[NCAT];     // folded per-category constant
    __shared__ float s_lmax, s_lsum;
    __shared__ float comb_m[NW * 64];
    __shared__ float comb_s[NW * 64];

    const int tid  = threadIdx.x;
    const int w    = tid >> 6;      // wave id 0..7
    const int lane = tid & 63;
    const int row  = blockIdx.x * 64 + lane;

    // --- Phase A: load z row, compute 2 g-columns per wave + zz (wave 0) ---
    const float* zr = z + row * DD;
    float zv[DD];
    #pragma unroll
    for (int i = 0; i < 4; ++i) {
        float4 v = reinterpret_cast<const float4*>(zr)[i];
        zv[4 * i + 0] = v.x; zv[4 * i + 1] = v.y;
        zv[4 * i + 2] = v.z; zv[4 * i + 3] = v.w;
    }
    {
        const int k0 = 2 * w, k1 = 2 * w + 1;
        float g0 = 0.f, g1 = 0.f;
        #pragma unroll
        for (int d = 0; d < DD; ++d) {
            g0 += zv[d] * mu[d * KK + k0];
            g1 += zv[d] * mu[d * KK + k1];
        }
        g_s[lane * GS + k0] = g0;
        g_s[lane * GS + k1] = g1;
    }
    if (w == 0) {
        float zz = 0.f;
        #pragma unroll
        for (int d = 0; d < DD; ++d) zz += zv[d] * zv[d];
        zz_s[lane] = zz;
    }
    // --- wave 1: softmax stats for pi (lmax, lsum) ---
    if (w == 1) {
        float pv[3];
        float lmax = -1e30f;
        #pragma unroll
        for (int j = 0; j < 3; ++j) {
            int c = lane + j * 64;
            pv[j] = (c < NCAT) ? pi[c] : -1e30f;
            lmax = fmaxf(lmax, pv[j]);
        }
        #pragma unroll
        for (int off = 32; off > 0; off >>= 1)
            lmax = fmaxf(lmax, __shfl_xor(lmax, off, 64));
        float lsum = 0.f;
        #pragma unroll
        for (int j = 0; j < 3; ++j) {
            int c = lane + j * 64;
            if (c < NCAT) lsum += __expf(pv[j] - lmax);
        }
        #pragma unroll
        for (int off = 32; off > 0; off >>= 1)
            lsum += __shfl_xor(lsum, off, 64);
        if (lane == 0) { s_lmax = lmax; s_lsum = lsum; }
    }
    __syncthreads();

    // --- Phase B: per-category constants (threads 0..135) ---
    if (tid < NCAT) {
        const int c = tid;
        int a = 0, rem = c;
        while (rem >= KK - a) { rem -= KK - a; ++a; }
        const int b = a + rem;

        float inv = 0.f, Cc = 0.f, mb2 = 0.f;
        #pragma unroll
        for (int d = 0; d < DD; ++d) {
            float mb = mu[d * KK + b];
            float ma = mu[d * KK + a];
            float al = mb - ma;
            inv += al * al;
            Cc  += al * mb;
            mb2 += mb * mb;
        }
        float recip   = (a == b) ? 0.f : 1.f / inv;
        float clipped = fminf(fmaxf(inv, 1e-12f), 1e30f);

        float p = __expf(pi[c] - s_lmax) / s_lsum;
        p = fminf(fmaxf(p, EPSF), 1.0f);
        float logpi = __logf(p);

        float k0;
        if (a == b) k0 = logpi - 8.f * LOG2PI_F;
        else        k0 = logpi - 8.f * LOG2PI_F + 0.5f * (LOG2PI_F - __logf(clipped));

        sRecip[c] = recip;
        sInv[c]   = inv;
        sSq[c]    = sqrtf(clipped);
        sC[c]     = Cc;
        sMB2[c]   = mb2;
        sK0[c]    = k0;
    }
    __syncthreads();

    // --- Phase C: wave w processes cats [17w, 17w+17) for row = lane ---
    {
        const int c0 = w * CPW;
        int a = 0, rem = c0;
        while (rem >= KK - a) { rem -= KK - a; ++a; }
        int b = a + rem;

        const float zz = zz_s[lane];
        const float* grow = &g_s[lane * GS];
        float m = -1e30f, s = 0.f;

        for (int i = 0; i < CPW; ++i) {
            const int c = c0 + i;
            float ga = grow[a];
            float gb = grow[b];
            float bsq = zz - 2.f * gb + sMB2[c];
            float val;
            if (a == b) {                       // wave-uniform branch
                val = sK0[c] - 0.5f * bsq;
            } else {
                float nu = -(gb - ga - sC[c]) * sRecip[c];
                float t  = nu * nu * sInv[c] - bsq;
                float sq = sSq[c];
                float e1 = (1.f - nu) * sq * INV_SQRT2;
                float e2 = (-nu) * sq * INV_SQRT2;
                float cd = 0.5f * (erff(e1) - erff(e2));
                cd = fminf(fmaxf(cd, EPSF), 1e30f);
                val = sK0[c] + 0.5f * t + __logf(cd);
            }
            float nm = fmaxf(m, val);
            s = s * __expf(m - nm) + __expf(val - nm);
            m = nm;
            if (++b == KK) { ++a; b = a; }      // advance (a,b), uniform
        }
        comb_m[w * 64 + lane] = m;
        comb_s[w * 64 + lane] = s;
    }
    __syncthreads();

    // --- merge 8 wave-partials per row, then block-sum (wave 0) ---
    if (w == 0) {
        float M = comb_m[lane], S = comb_s[lane];
        #pragma unroll
        for (int ww = 1; ww < NW; ++ww) {
            float mm = comb_m[ww * 64 + lane];
            float ss = comb_s[ww * 64 + lane];
            float nm = fmaxf(M, mm);
            S = S * __expf(M - nm) + ss * __expf(mm - nm);
            M = nm;
        }
        float lp = M + __logf(S);
        #pragma unroll
        for (int off = 32; off > 0; off >>= 1)
            lp += __shfl_xor(lp, off, 64);
        if (lane == 0) partials[blockIdx.x] = lp;
    }
}

// ---------------------------------------------------------------------------
// Final reduction: sum 320 block partials, divide by NROWS.
// ---------------------------------------------------------------------------
__global__ __launch_bounds__(64) void latent_reduce(
    const float* __restrict__ partials, float* __restrict__ out, int n)
{
    const int tid = threadIdx.x;
    float s = 0.f;
    for (int i = tid; i < n; i += 64) s += partials[i];
    #pragma unroll
    for (int off = 32; off > 0; off >>= 1)
        s += __shfl_xor(s, off, 64);
    if (tid == 0) out[0] = s * (1.0f / (float)NROWS);
}

extern "C" void kernel_launch(void* const* d_in, const int* in_sizes, int n_in,
                              void* d_out, int out_size, void* d_ws, size_t ws_size,
                              hipStream_t stream) {
    const float* z  = (const float*)d_in[0];   // (2048,10,16) f32
    const float* pi = (const float*)d_in[1];   // (1,136) f32
    const float* mu = (const float*)d_in[2];   // (16,16) f32
    float* out      = (float*)d_out;           // scalar f32
    float* partials = (float*)d_ws;

    const int nblocks = NROWS / 64;            // 320 blocks x 512 threads
    latent_main<<<nblocks, 512, 0, stream>>>(z, pi, mu, partials);
    latent_reduce<<<1, 64, 0, stream>>>(partials, out, nblocks);
}